// Round 7
// baseline (229.219 us; speedup 1.0000x reference)
//
#include <hip/hip_runtime.h>
#include <math.h>

// EdgeConditionedConv on MI355X — round 6: 8-wave j-split edge_msg.
// Round-5 analysis: MFMA pipe issues at-rate but only 31% duty; occupancy
// grid-capped at 3 blocks/CU x 4 waves. Now 512-thread blocks, wave=(mt,jh),
// jh halves the j-range -> 2x resident waves (24/CU), dual msgred buffers
// summed at scatter. Same MFMA count, same Wpk traffic.

constexpr int N_NODES  = 25000;
constexpr int N_EDGES  = 50000;
constexpr int NODE_DIM = 64;
constexpr int EDGE_DIM = 16;
constexpr int HID      = 128;

typedef __attribute__((ext_vector_type(8))) _Float16 half8;
typedef __attribute__((ext_vector_type(4))) float    f32x4;

constexpr int G_MS  = 128;             // agg-zero blocks
constexpr int G_PK  = 355;             // prepack blocks
constexpr int G_MLP = N_EDGES / 8;     // mlp1 blocks (8 edges each)

// ---------------------------------------------------------------- prep
__global__ __launch_bounds__(256) void prep_kernel(
    const float* __restrict__ W2, const float* __restrict__ b2,
    const float* __restrict__ w_ih, const float* __restrict__ w_hh,
    const float* __restrict__ edge_attr, const float* __restrict__ W1,
    const float* __restrict__ b1,
    _Float16* __restrict__ Wpk, _Float16* __restrict__ b2pk,
    float* __restrict__ wTih, float* __restrict__ wThh,
    _Float16* __restrict__ h, float* __restrict__ agg)
{
    int b = blockIdx.x;
    if (b < G_MS) {
        float4* a4 = (float4*)agg;
        const float4 z = make_float4(0.f, 0.f, 0.f, 0.f);
        for (int i = b * 256 + threadIdx.x; i < N_NODES * NODE_DIM / 4; i += G_MS * 256)
            a4[i] = z;
        return;
    }
    if (b < G_MS + G_PK) {
        int c = (b - G_MS) * 256 + threadIdx.x;
        if (c < 65536) {
            int lane = c & 63, mt = (c >> 6) & 3, ks = (c >> 8) & 3, j = c >> 10;
            int i   = mt * 16 + (lane & 15);
            int col = ks * 32 + ((lane >> 4) & 3) * 8;
            const float* src = W2 + (size_t)(i * 64 + j) * HID + col;
            half8 o;
#pragma unroll
            for (int q = 0; q < 8; ++q) o[q] = (_Float16)src[q];
            ((half8*)Wpk)[c] = o;
        } else if (c < 65536 + 512) {
            int c2 = c - 65536;
            int lane = c2 & 63, mt = (c2 >> 6) & 3, ks2 = (c2 >> 8) & 1;
            int i = mt * 16 + (lane & 15);
            int j = ks2 * 32 + ((lane >> 4) & 3) * 8;
            const float* src = b2 + i * 64 + j;
            half8 o;
#pragma unroll
            for (int q = 0; q < 8; ++q) o[q] = (_Float16)src[q];
            ((half8*)b2pk)[c2] = o;
        } else if (c < 65536 + 512 + 2 * 12288) {
            int idx = c - (65536 + 512);
            const float* src = (idx < 12288) ? w_ih : w_hh;
            float*       dst = (idx < 12288) ? wTih : wThh;
            int e2 = (idx < 12288) ? idx : idx - 12288;
            int k = e2 / 192, g = e2 - k * 192;
            dst[k * 192 + g] = src[(size_t)g * 64 + k];
        }
        return;
    }
    // mlp1: 8 edges per block
    int ebase = (b - G_MS - G_PK) * 8;
    int k = threadIdx.x & 127;
    const float* w = W1 + (size_t)k * EDGE_DIM;
#pragma unroll
    for (int p = 0; p < 4; ++p) {
        int e = ebase + p * 2 + (threadIdx.x >> 7);
        if (e >= N_EDGES) break;
        const float* ea = edge_attr + (size_t)e * EDGE_DIM;
        float acc = b1[k];
#pragma unroll
        for (int d = 0; d < EDGE_DIM; ++d) acc += ea[d] * w[d];
        float g = 0.5f * acc * (1.0f + erff(acc * 0.70710678118654752f));
        h[(size_t)e * HID + k] = (_Float16)g;
    }
}

// ---------------------------------------------------------------- phase 2
// 8 waves: wave = (jh, mt). mt owns 16 output rows, jh owns half the j-range.
__global__ __launch_bounds__(512, 4) void edge_msg_mfma_kernel(
    const _Float16* __restrict__ hbuf,
    const float*    __restrict__ x,
    const int*      __restrict__ edge_index,   // [2][E] int32
    const _Float16* __restrict__ Wpk,
    const _Float16* __restrict__ b2pk,
    float* __restrict__ agg)                   // [N][64], pre-zeroed
{
    __shared__ float xsh[64 * 68];        // gathered x[src], pitch 68
    __shared__ float msgred[2][64 * 67];  // [jh][i][e], pitch 67
    __shared__ int   dsts[64];

    const int e0   = blockIdx.x * 64;
    const int t    = threadIdx.x;
    const int wave = t >> 6;
    const int lane = t & 63;
    const int mt   = wave & 3;
    const int jh   = wave >> 2;

    // ---- gather x[src[e]] rows into xsh (zero-fill invalid) + dsts
    if (t < 64) dsts[t] = (e0 + t < N_EDGES) ? edge_index[N_EDGES + e0 + t] : -1;
#pragma unroll
    for (int r = 0; r < 2; ++r) {
        int idx = t + r * 512;            // 0..1023 float4 slots
        int le = idx >> 4, q = idx & 15;
        int e = e0 + le;
        float4 v = make_float4(0.f, 0.f, 0.f, 0.f);
        if (e < N_EDGES) {
            int s = edge_index[e];
            if ((unsigned)s < (unsigned)N_NODES)
                v = ((const float4*)x)[(size_t)s * 16 + q];
        }
        *(float4*)&xsh[le * 68 + q * 4] = v;
    }

    // ---- per-wave resident h fragments (B operand)
    half8 hf[4][4];   // [nt][ks]
#pragma unroll
    for (int nt = 0; nt < 4; ++nt) {
#pragma unroll
        for (int ks = 0; ks < 4; ++ks) {
            int el = nt * 16 + (lane & 15);
            int ee = e0 + el; if (ee >= N_EDGES) ee = N_EDGES - 1;
            int gk = ks * 32 + ((lane >> 4) & 3) * 8;
            hf[nt][ks] = *(const half8*)(hbuf + (size_t)ee * HID + gk);
        }
    }
    __syncthreads();

    const f32x4 zero4 = {0.f, 0.f, 0.f, 0.f};
    f32x4 msg[4];
#pragma unroll
    for (int nt = 0; nt < 4; ++nt) msg[nt] = zero4;

    const half8* wpk8 = (const half8*)Wpk;
    const int mbase = mt * 64 + lane;
    const int j0 = jh * 32;

    half8 aA[4], aB[4];
#pragma unroll
    for (int ks = 0; ks < 4; ++ks) aA[ks] = wpk8[(size_t)j0 * 1024 + mbase + ks * 256];

#pragma unroll 1
    for (int j = j0; j < j0 + 32; j += 2) {
        {   // prefetch j+1
            size_t nb = (size_t)(j + 1) * 1024 + mbase;
#pragma unroll
            for (int ks = 0; ks < 4; ++ks) aB[ks] = wpk8[nb + ks * 256];
        }
        {   // compute j
            float gv[4];
#pragma unroll
            for (int nt = 0; nt < 4; ++nt) gv[nt] = xsh[(nt * 16 + (lane & 15)) * 68 + j];
            f32x4 P[4];
#pragma unroll
            for (int ks = 0; ks < 4; ++ks)
#pragma unroll
                for (int nt = 0; nt < 4; ++nt)
                    P[nt] = __builtin_amdgcn_mfma_f32_16x16x32_f16(
                        aA[ks], hf[nt][ks], ks == 0 ? zero4 : P[nt], 0, 0, 0);
#pragma unroll
            for (int nt = 0; nt < 4; ++nt)
#pragma unroll
                for (int r = 0; r < 4; ++r) msg[nt][r] += gv[nt] * P[nt][r];
        }
        if (j + 2 < j0 + 32) {   // prefetch j+2
            size_t nb = (size_t)(j + 2) * 1024 + mbase;
#pragma unroll
            for (int ks = 0; ks < 4; ++ks) aA[ks] = wpk8[nb + ks * 256];
        }
        {   // compute j+1
            float gv[4];
#pragma unroll
            for (int nt = 0; nt < 4; ++nt) gv[nt] = xsh[(nt * 16 + (lane & 15)) * 68 + j + 1];
            f32x4 P[4];
#pragma unroll
            for (int ks = 0; ks < 4; ++ks)
#pragma unroll
                for (int nt = 0; nt < 4; ++nt)
                    P[nt] = __builtin_amdgcn_mfma_f32_16x16x32_f16(
                        aB[ks], hf[nt][ks], ks == 0 ? zero4 : P[nt], 0, 0, 0);
#pragma unroll
            for (int nt = 0; nt < 4; ++nt)
#pragma unroll
                for (int r = 0; r < 4; ++r) msg[nt][r] += gv[nt] * P[nt][r];
        }
    }

    // ---- bias (jh==0 waves only): msg[i,e] += sum_j b2[i*64+j]*g[e,j]
    if (jh == 0) {
#pragma unroll
        for (int ks2 = 0; ks2 < 2; ++ks2) {
            half8 gf[4];
#pragma unroll
            for (int nt = 0; nt < 4; ++nt) {
                const float* gp = &xsh[(nt * 16 + (lane & 15)) * 68 + ks2 * 32 + ((lane >> 4) & 3) * 8];
                float4 lo = *(const float4*)gp;
                float4 hi = *(const float4*)(gp + 4);
                half8 g8;
                g8[0] = (_Float16)lo.x; g8[1] = (_Float16)lo.y;
                g8[2] = (_Float16)lo.z; g8[3] = (_Float16)lo.w;
                g8[4] = (_Float16)hi.x; g8[5] = (_Float16)hi.y;
                g8[6] = (_Float16)hi.z; g8[7] = (_Float16)hi.w;
                gf[nt] = g8;
            }
            half8 bf8 = ((const half8*)b2pk)[ks2 * 256 + mt * 64 + lane];
#pragma unroll
            for (int nt = 0; nt < 4; ++nt)
                msg[nt] = __builtin_amdgcn_mfma_f32_16x16x32_f16(bf8, gf[nt], msg[nt], 0, 0, 0);
        }
    }

    // ---- each wave writes its exclusive 16 rows of msgred[jh]
#pragma unroll
    for (int nt = 0; nt < 4; ++nt)
#pragma unroll
        for (int r = 0; r < 4; ++r) {
            int i = mt * 16 + ((lane >> 4) & 3) * 4 + r;
            int e = nt * 16 + (lane & 15);
            msgred[jh][i * 67 + e] = msg[nt][r];
        }
    __syncthreads();

    // ---- scatter: sum the two jh-halves, one edge row per atomic instr
#pragma unroll 1
    for (int ee = wave; ee < 64; ee += 8) {
        int d = dsts[ee];
        if (e0 + ee < N_EDGES && (unsigned)d < (unsigned)N_NODES) {
            float v = msgred[0][lane * 67 + ee] + msgred[1][lane * 67 + ee];
            atomicAdd(agg + (size_t)d * NODE_DIM + lane, v);
        }
    }
}

// ---------------------------------------------------------------- phase 3
__global__ __launch_bounds__(256) void gru_kernel(
    const float* __restrict__ agg,
    const float* __restrict__ x,
    const float* __restrict__ wTih,   // [64][192]
    const float* __restrict__ wThh,   // [64][192]
    const float* __restrict__ b_ih,
    const float* __restrict__ b_hh,
    float* __restrict__ out)
{
    __shared__ float as_[32][64], xs_[32][64];
    const int t    = threadIdx.x;
    const int wave = t >> 6, lane = t & 63;
    const int n0   = blockIdx.x * 32;

    {
        const float4* asrc = (const float4*)(agg + (size_t)n0 * 64);
        const float4* xsrc = (const float4*)(x   + (size_t)n0 * 64);
        float4* ad = (float4*)&as_[0][0];
        float4* xd = (float4*)&xs_[0][0];
        int nvalid4 = min(N_NODES - n0, 32) * 16;
#pragma unroll
        for (int r = 0; r < 2; ++r) {
            int idx = t + r * 256;
            float4 v = make_float4(0.f, 0.f, 0.f, 0.f), u = v;
            if (idx < nvalid4) { v = asrc[idx]; u = xsrc[idx]; }
            ad[idx] = v; xd[idx] = u;
        }
    }
    __syncthreads();

    float accI0[8] = {}, accI1[8] = {}, accI2[8] = {};
    float accH0[8] = {}, accH1[8] = {}, accH2[8] = {};

#pragma unroll 4
    for (int k = 0; k < 64; ++k) {
        float wi0 = wTih[k * 192 + lane];
        float wi1 = wTih[k * 192 + 64 + lane];
        float wi2 = wTih[k * 192 + 128 + lane];
        float wh0 = wThh[k * 192 + lane];
        float wh1 = wThh[k * 192 + 64 + lane];
        float wh2 = wThh[k * 192 + 128 + lane];
#pragma unroll
        for (int n = 0; n < 8; ++n) {
            float a  = as_[wave * 8 + n][k];
            float xx = xs_[wave * 8 + n][k];
            accI0[n] += a * wi0;  accI1[n] += a * wi1;  accI2[n] += a * wi2;
            accH0[n] += xx * wh0; accH1[n] += xx * wh1; accH2[n] += xx * wh2;
        }
    }

    float bi0 = b_ih[lane], bi1 = b_ih[64 + lane], bi2 = b_ih[128 + lane];
    float bh0 = b_hh[lane], bh1 = b_hh[64 + lane], bh2 = b_hh[128 + lane];
#pragma unroll
    for (int n = 0; n < 8; ++n) {
        int node = n0 + wave * 8 + n;
        if (node >= N_NODES) break;
        float r  = 1.f / (1.f + expf(-(accI0[n] + bi0 + accH0[n] + bh0)));
        float z  = 1.f / (1.f + expf(-(accI1[n] + bi1 + accH1[n] + bh1)));
        float nn = tanhf(accI2[n] + bi2 + r * (accH2[n] + bh2));
        out[(size_t)node * 64 + lane] = (1.f - z) * nn + z * xs_[wave * 8 + n][lane];
    }
}

// ---------------------------------------------------------------- launch
extern "C" void kernel_launch(void* const* d_in, const int* in_sizes, int n_in,
                              void* d_out, int out_size, void* d_ws, size_t ws_size,
                              hipStream_t stream)
{
    const float* x          = (const float*)d_in[0];
    const int*   edge_index = (const int*)  d_in[1];
    const float* edge_attr  = (const float*)d_in[2];
    const float* W1         = (const float*)d_in[3];
    const float* b1         = (const float*)d_in[4];
    const float* W2         = (const float*)d_in[5];
    const float* b2         = (const float*)d_in[6];
    const float* w_ih       = (const float*)d_in[7];
    const float* w_hh       = (const float*)d_in[8];
    const float* b_ih       = (const float*)d_in[9];
    const float* b_hh       = (const float*)d_in[10];
    float* out = (float*)d_out;

    char* ws = (char*)d_ws;
    _Float16* hbuf = (_Float16*)ws;                         // 12.8 MB
    ws += (size_t)N_EDGES * HID * sizeof(_Float16);
    _Float16* Wpk  = (_Float16*)ws;                         // 1 MB
    ws += (size_t)65536 * 8 * sizeof(_Float16);
    _Float16* b2pk = (_Float16*)ws;                         // 8 KB
    ws += (size_t)512 * 8 * sizeof(_Float16);
    float* wTih = (float*)ws;                               // 48 KB
    ws += (size_t)64 * 192 * sizeof(float);
    float* wThh = (float*)ws;                               // 48 KB
    ws += (size_t)64 * 192 * sizeof(float);
    float* agg = (float*)ws;                                // 6.4 MB

    prep_kernel<<<dim3(G_MS + G_PK + G_MLP), dim3(256), 0, stream>>>(
        W2, b2, w_ih, w_hh, edge_attr, W1, b1,
        Wpk, b2pk, wTih, wThh, hbuf, agg);

    edge_msg_mfma_kernel<<<dim3((N_EDGES + 63) / 64), dim3(512), 0, stream>>>(
        hbuf, x, edge_index, Wpk, b2pk, agg);

    gru_kernel<<<dim3((N_NODES + 31) / 32), dim3(256), 0, stream>>>(
        agg, x, wTih, wThh, b_ih, b_hh, out);
}

// Round 8
// 153.700 us; speedup vs baseline: 1.4913x; 1.4913x over previous
//
#include <hip/hip_runtime.h>
#include <math.h>

// EdgeConditionedConv on MI355X — round 7: round 6's 8-wave j-split with the
// launch_bounds spill fixed. (512,4) had forced VGPR=64 -> 110 MB scratch
// traffic; (512,2) lets the allocator keep the ~84-reg live set resident.

constexpr int N_NODES  = 25000;
constexpr int N_EDGES  = 50000;
constexpr int NODE_DIM = 64;
constexpr int EDGE_DIM = 16;
constexpr int HID      = 128;

typedef __attribute__((ext_vector_type(8))) _Float16 half8;
typedef __attribute__((ext_vector_type(4))) float    f32x4;

constexpr int G_MS  = 128;             // agg-zero blocks
constexpr int G_PK  = 355;             // prepack blocks
constexpr int G_MLP = N_EDGES / 8;     // mlp1 blocks (8 edges each)

// ---------------------------------------------------------------- prep
__global__ __launch_bounds__(256) void prep_kernel(
    const float* __restrict__ W2, const float* __restrict__ b2,
    const float* __restrict__ w_ih, const float* __restrict__ w_hh,
    const float* __restrict__ edge_attr, const float* __restrict__ W1,
    const float* __restrict__ b1,
    _Float16* __restrict__ Wpk, _Float16* __restrict__ b2pk,
    float* __restrict__ wTih, float* __restrict__ wThh,
    _Float16* __restrict__ h, float* __restrict__ agg)
{
    int b = blockIdx.x;
    if (b < G_MS) {
        float4* a4 = (float4*)agg;
        const float4 z = make_float4(0.f, 0.f, 0.f, 0.f);
        for (int i = b * 256 + threadIdx.x; i < N_NODES * NODE_DIM / 4; i += G_MS * 256)
            a4[i] = z;
        return;
    }
    if (b < G_MS + G_PK) {
        int c = (b - G_MS) * 256 + threadIdx.x;
        if (c < 65536) {
            int lane = c & 63, mt = (c >> 6) & 3, ks = (c >> 8) & 3, j = c >> 10;
            int i   = mt * 16 + (lane & 15);
            int col = ks * 32 + ((lane >> 4) & 3) * 8;
            const float* src = W2 + (size_t)(i * 64 + j) * HID + col;
            half8 o;
#pragma unroll
            for (int q = 0; q < 8; ++q) o[q] = (_Float16)src[q];
            ((half8*)Wpk)[c] = o;
        } else if (c < 65536 + 512) {
            int c2 = c - 65536;
            int lane = c2 & 63, mt = (c2 >> 6) & 3, ks2 = (c2 >> 8) & 1;
            int i = mt * 16 + (lane & 15);
            int j = ks2 * 32 + ((lane >> 4) & 3) * 8;
            const float* src = b2 + i * 64 + j;
            half8 o;
#pragma unroll
            for (int q = 0; q < 8; ++q) o[q] = (_Float16)src[q];
            ((half8*)b2pk)[c2] = o;
        } else if (c < 65536 + 512 + 2 * 12288) {
            int idx = c - (65536 + 512);
            const float* src = (idx < 12288) ? w_ih : w_hh;
            float*       dst = (idx < 12288) ? wTih : wThh;
            int e2 = (idx < 12288) ? idx : idx - 12288;
            int k = e2 / 192, g = e2 - k * 192;
            dst[k * 192 + g] = src[(size_t)g * 64 + k];
        }
        return;
    }
    // mlp1: 8 edges per block
    int ebase = (b - G_MS - G_PK) * 8;
    int k = threadIdx.x & 127;
    const float* w = W1 + (size_t)k * EDGE_DIM;
#pragma unroll
    for (int p = 0; p < 4; ++p) {
        int e = ebase + p * 2 + (threadIdx.x >> 7);
        if (e >= N_EDGES) break;
        const float* ea = edge_attr + (size_t)e * EDGE_DIM;
        float acc = b1[k];
#pragma unroll
        for (int d = 0; d < EDGE_DIM; ++d) acc += ea[d] * w[d];
        float g = 0.5f * acc * (1.0f + erff(acc * 0.70710678118654752f));
        h[(size_t)e * HID + k] = (_Float16)g;
    }
}

// ---------------------------------------------------------------- phase 2
// 8 waves: wave = (jh, mt). mt owns 16 output rows, jh owns half the j-range.
__global__ __launch_bounds__(512, 2) void edge_msg_mfma_kernel(
    const _Float16* __restrict__ hbuf,
    const float*    __restrict__ x,
    const int*      __restrict__ edge_index,   // [2][E] int32
    const _Float16* __restrict__ Wpk,
    const _Float16* __restrict__ b2pk,
    float* __restrict__ agg)                   // [N][64], pre-zeroed
{
    __shared__ float xsh[64 * 68];        // gathered x[src], pitch 68
    __shared__ float msgred[2][64 * 67];  // [jh][i][e], pitch 67
    __shared__ int   dsts[64];

    const int e0   = blockIdx.x * 64;
    const int t    = threadIdx.x;
    const int wave = t >> 6;
    const int lane = t & 63;
    const int mt   = wave & 3;
    const int jh   = wave >> 2;

    // ---- gather x[src[e]] rows into xsh (zero-fill invalid) + dsts
    if (t < 64) dsts[t] = (e0 + t < N_EDGES) ? edge_index[N_EDGES + e0 + t] : -1;
#pragma unroll
    for (int r = 0; r < 2; ++r) {
        int idx = t + r * 512;            // 0..1023 float4 slots
        int le = idx >> 4, q = idx & 15;
        int e = e0 + le;
        float4 v = make_float4(0.f, 0.f, 0.f, 0.f);
        if (e < N_EDGES) {
            int s = edge_index[e];
            if ((unsigned)s < (unsigned)N_NODES)
                v = ((const float4*)x)[(size_t)s * 16 + q];
        }
        *(float4*)&xsh[le * 68 + q * 4] = v;
    }

    // ---- per-wave resident h fragments (B operand)
    half8 hf[4][4];   // [nt][ks]
#pragma unroll
    for (int nt = 0; nt < 4; ++nt) {
#pragma unroll
        for (int ks = 0; ks < 4; ++ks) {
            int el = nt * 16 + (lane & 15);
            int ee = e0 + el; if (ee >= N_EDGES) ee = N_EDGES - 1;
            int gk = ks * 32 + ((lane >> 4) & 3) * 8;
            hf[nt][ks] = *(const half8*)(hbuf + (size_t)ee * HID + gk);
        }
    }
    __syncthreads();

    const f32x4 zero4 = {0.f, 0.f, 0.f, 0.f};
    f32x4 msg[4];
#pragma unroll
    for (int nt = 0; nt < 4; ++nt) msg[nt] = zero4;

    const half8* wpk8 = (const half8*)Wpk;
    const int mbase = mt * 64 + lane;
    const int j0 = jh * 32;

    half8 aA[4], aB[4];
#pragma unroll
    for (int ks = 0; ks < 4; ++ks) aA[ks] = wpk8[(size_t)j0 * 1024 + mbase + ks * 256];

#pragma unroll 1
    for (int j = j0; j < j0 + 32; j += 2) {
        {   // prefetch j+1
            size_t nb = (size_t)(j + 1) * 1024 + mbase;
#pragma unroll
            for (int ks = 0; ks < 4; ++ks) aB[ks] = wpk8[nb + ks * 256];
        }
        {   // compute j
            float gv[4];
#pragma unroll
            for (int nt = 0; nt < 4; ++nt) gv[nt] = xsh[(nt * 16 + (lane & 15)) * 68 + j];
            f32x4 P[4];
#pragma unroll
            for (int ks = 0; ks < 4; ++ks)
#pragma unroll
                for (int nt = 0; nt < 4; ++nt)
                    P[nt] = __builtin_amdgcn_mfma_f32_16x16x32_f16(
                        aA[ks], hf[nt][ks], ks == 0 ? zero4 : P[nt], 0, 0, 0);
#pragma unroll
            for (int nt = 0; nt < 4; ++nt)
#pragma unroll
                for (int r = 0; r < 4; ++r) msg[nt][r] += gv[nt] * P[nt][r];
        }
        if (j + 2 < j0 + 32) {   // prefetch j+2
            size_t nb = (size_t)(j + 2) * 1024 + mbase;
#pragma unroll
            for (int ks = 0; ks < 4; ++ks) aA[ks] = wpk8[nb + ks * 256];
        }
        {   // compute j+1
            float gv[4];
#pragma unroll
            for (int nt = 0; nt < 4; ++nt) gv[nt] = xsh[(nt * 16 + (lane & 15)) * 68 + j + 1];
            f32x4 P[4];
#pragma unroll
            for (int ks = 0; ks < 4; ++ks)
#pragma unroll
                for (int nt = 0; nt < 4; ++nt)
                    P[nt] = __builtin_amdgcn_mfma_f32_16x16x32_f16(
                        aB[ks], hf[nt][ks], ks == 0 ? zero4 : P[nt], 0, 0, 0);
#pragma unroll
            for (int nt = 0; nt < 4; ++nt)
#pragma unroll
                for (int r = 0; r < 4; ++r) msg[nt][r] += gv[nt] * P[nt][r];
        }
    }

    // ---- bias (jh==0 waves only): msg[i,e] += sum_j b2[i*64+j]*g[e,j]
    if (jh == 0) {
#pragma unroll
        for (int ks2 = 0; ks2 < 2; ++ks2) {
            half8 gf[4];
#pragma unroll
            for (int nt = 0; nt < 4; ++nt) {
                const float* gp = &xsh[(nt * 16 + (lane & 15)) * 68 + ks2 * 32 + ((lane >> 4) & 3) * 8];
                float4 lo = *(const float4*)gp;
                float4 hi = *(const float4*)(gp + 4);
                half8 g8;
                g8[0] = (_Float16)lo.x; g8[1] = (_Float16)lo.y;
                g8[2] = (_Float16)lo.z; g8[3] = (_Float16)lo.w;
                g8[4] = (_Float16)hi.x; g8[5] = (_Float16)hi.y;
                g8[6] = (_Float16)hi.z; g8[7] = (_Float16)hi.w;
                gf[nt] = g8;
            }
            half8 bf8 = ((const half8*)b2pk)[ks2 * 256 + mt * 64 + lane];
#pragma unroll
            for (int nt = 0; nt < 4; ++nt)
                msg[nt] = __builtin_amdgcn_mfma_f32_16x16x32_f16(bf8, gf[nt], msg[nt], 0, 0, 0);
        }
    }

    // ---- each wave writes its exclusive 16 rows of msgred[jh]
#pragma unroll
    for (int nt = 0; nt < 4; ++nt)
#pragma unroll
        for (int r = 0; r < 4; ++r) {
            int i = mt * 16 + ((lane >> 4) & 3) * 4 + r;
            int e = nt * 16 + (lane & 15);
            msgred[jh][i * 67 + e] = msg[nt][r];
        }
    __syncthreads();

    // ---- scatter: sum the two jh-halves, one edge row per atomic instr
#pragma unroll 1
    for (int ee = wave; ee < 64; ee += 8) {
        int d = dsts[ee];
        if (e0 + ee < N_EDGES && (unsigned)d < (unsigned)N_NODES) {
            float v = msgred[0][lane * 67 + ee] + msgred[1][lane * 67 + ee];
            atomicAdd(agg + (size_t)d * NODE_DIM + lane, v);
        }
    }
}

// ---------------------------------------------------------------- phase 3
__global__ __launch_bounds__(256) void gru_kernel(
    const float* __restrict__ agg,
    const float* __restrict__ x,
    const float* __restrict__ wTih,   // [64][192]
    const float* __restrict__ wThh,   // [64][192]
    const float* __restrict__ b_ih,
    const float* __restrict__ b_hh,
    float* __restrict__ out)
{
    __shared__ float as_[32][64], xs_[32][64];
    const int t    = threadIdx.x;
    const int wave = t >> 6, lane = t & 63;
    const int n0   = blockIdx.x * 32;

    {
        const float4* asrc = (const float4*)(agg + (size_t)n0 * 64);
        const float4* xsrc = (const float4*)(x   + (size_t)n0 * 64);
        float4* ad = (float4*)&as_[0][0];
        float4* xd = (float4*)&xs_[0][0];
        int nvalid4 = min(N_NODES - n0, 32) * 16;
#pragma unroll
        for (int r = 0; r < 2; ++r) {
            int idx = t + r * 256;
            float4 v = make_float4(0.f, 0.f, 0.f, 0.f), u = v;
            if (idx < nvalid4) { v = asrc[idx]; u = xsrc[idx]; }
            ad[idx] = v; xd[idx] = u;
        }
    }
    __syncthreads();

    float accI0[8] = {}, accI1[8] = {}, accI2[8] = {};
    float accH0[8] = {}, accH1[8] = {}, accH2[8] = {};

#pragma unroll 4
    for (int k = 0; k < 64; ++k) {
        float wi0 = wTih[k * 192 + lane];
        float wi1 = wTih[k * 192 + 64 + lane];
        float wi2 = wTih[k * 192 + 128 + lane];
        float wh0 = wThh[k * 192 + lane];
        float wh1 = wThh[k * 192 + 64 + lane];
        float wh2 = wThh[k * 192 + 128 + lane];
#pragma unroll
        for (int n = 0; n < 8; ++n) {
            float a  = as_[wave * 8 + n][k];
            float xx = xs_[wave * 8 + n][k];
            accI0[n] += a * wi0;  accI1[n] += a * wi1;  accI2[n] += a * wi2;
            accH0[n] += xx * wh0; accH1[n] += xx * wh1; accH2[n] += xx * wh2;
        }
    }

    float bi0 = b_ih[lane], bi1 = b_ih[64 + lane], bi2 = b_ih[128 + lane];
    float bh0 = b_hh[lane], bh1 = b_hh[64 + lane], bh2 = b_hh[128 + lane];
#pragma unroll
    for (int n = 0; n < 8; ++n) {
        int node = n0 + wave * 8 + n;
        if (node >= N_NODES) break;
        float r  = 1.f / (1.f + expf(-(accI0[n] + bi0 + accH0[n] + bh0)));
        float z  = 1.f / (1.f + expf(-(accI1[n] + bi1 + accH1[n] + bh1)));
        float nn = tanhf(accI2[n] + bi2 + r * (accH2[n] + bh2));
        out[(size_t)node * 64 + lane] = (1.f - z) * nn + z * xs_[wave * 8 + n][lane];
    }
}

// ---------------------------------------------------------------- launch
extern "C" void kernel_launch(void* const* d_in, const int* in_sizes, int n_in,
                              void* d_out, int out_size, void* d_ws, size_t ws_size,
                              hipStream_t stream)
{
    const float* x          = (const float*)d_in[0];
    const int*   edge_index = (const int*)  d_in[1];
    const float* edge_attr  = (const float*)d_in[2];
    const float* W1         = (const float*)d_in[3];
    const float* b1         = (const float*)d_in[4];
    const float* W2         = (const float*)d_in[5];
    const float* b2         = (const float*)d_in[6];
    const float* w_ih       = (const float*)d_in[7];
    const float* w_hh       = (const float*)d_in[8];
    const float* b_ih       = (const float*)d_in[9];
    const float* b_hh       = (const float*)d_in[10];
    float* out = (float*)d_out;

    char* ws = (char*)d_ws;
    _Float16* hbuf = (_Float16*)ws;                         // 12.8 MB
    ws += (size_t)N_EDGES * HID * sizeof(_Float16);
    _Float16* Wpk  = (_Float16*)ws;                         // 1 MB
    ws += (size_t)65536 * 8 * sizeof(_Float16);
    _Float16* b2pk = (_Float16*)ws;                         // 8 KB
    ws += (size_t)512 * 8 * sizeof(_Float16);
    float* wTih = (float*)ws;                               // 48 KB
    ws += (size_t)64 * 192 * sizeof(float);
    float* wThh = (float*)ws;                               // 48 KB
    ws += (size_t)64 * 192 * sizeof(float);
    float* agg = (float*)ws;                                // 6.4 MB

    prep_kernel<<<dim3(G_MS + G_PK + G_MLP), dim3(256), 0, stream>>>(
        W2, b2, w_ih, w_hh, edge_attr, W1, b1,
        Wpk, b2pk, wTih, wThh, hbuf, agg);

    edge_msg_mfma_kernel<<<dim3((N_EDGES + 63) / 64), dim3(512), 0, stream>>>(
        hbuf, x, edge_index, Wpk, b2pk, agg);

    gru_kernel<<<dim3((N_NODES + 31) / 32), dim3(256), 0, stream>>>(
        agg, x, wTih, wThh, b_ih, b_hh, out);
}

// Round 10
// 123.759 us; speedup vs baseline: 1.8521x; 1.2419x over previous
//
#include <hip/hip_runtime.h>
#include <math.h>

// EdgeConditionedConv on MI355X — round 9: recover from r8 failure.
// edge_msg reverted to the round-5 body EXACTLY (proven pass @70.5us).
// r8 lesson: ws usage grew past the proven 20,355,072 B (Wpk pad) and the
// last buffer (agg) likely ran off the end -> modest output corruption.
// Keep ws layout byte-identical to r5. New this round: GRU transposed-LDS
// staging (asT/xsT[k][node]) -> 4 broadcast ds_read_b128 per k instead of
// 16 scalar ds_read_b32.

constexpr int N_NODES  = 25000;
constexpr int N_EDGES  = 50000;
constexpr int NODE_DIM = 64;
constexpr int EDGE_DIM = 16;
constexpr int HID      = 128;

typedef __attribute__((ext_vector_type(8))) _Float16 half8;
typedef __attribute__((ext_vector_type(4))) float    f32x4;

constexpr int G_MS  = 128;             // agg-zero blocks
constexpr int G_PK  = 355;             // prepack blocks
constexpr int G_MLP = N_EDGES / 8;     // mlp1 blocks (8 edges each)

// ---------------------------------------------------------------- prep
__global__ __launch_bounds__(256) void prep_kernel(
    const float* __restrict__ W2, const float* __restrict__ b2,
    const float* __restrict__ w_ih, const float* __restrict__ w_hh,
    const float* __restrict__ edge_attr, const float* __restrict__ W1,
    const float* __restrict__ b1,
    _Float16* __restrict__ Wpk, _Float16* __restrict__ b2pk,
    float* __restrict__ wTih, float* __restrict__ wThh,
    _Float16* __restrict__ h, float* __restrict__ agg)
{
    int b = blockIdx.x;
    if (b < G_MS) {
        float4* a4 = (float4*)agg;
        const float4 z = make_float4(0.f, 0.f, 0.f, 0.f);
        for (int i = b * 256 + threadIdx.x; i < N_NODES * NODE_DIM / 4; i += G_MS * 256)
            a4[i] = z;
        return;
    }
    if (b < G_MS + G_PK) {
        int c = (b - G_MS) * 256 + threadIdx.x;
        if (c < 65536) {
            int lane = c & 63, mt = (c >> 6) & 3, ks = (c >> 8) & 3, j = c >> 10;
            int i   = mt * 16 + (lane & 15);
            int col = ks * 32 + ((lane >> 4) & 3) * 8;
            const float* src = W2 + (size_t)(i * 64 + j) * HID + col;
            half8 o;
#pragma unroll
            for (int q = 0; q < 8; ++q) o[q] = (_Float16)src[q];
            ((half8*)Wpk)[c] = o;
        } else if (c < 65536 + 512) {
            int c2 = c - 65536;
            int lane = c2 & 63, mt = (c2 >> 6) & 3, ks2 = (c2 >> 8) & 1;
            int i = mt * 16 + (lane & 15);
            int j = ks2 * 32 + ((lane >> 4) & 3) * 8;
            const float* src = b2 + i * 64 + j;
            half8 o;
#pragma unroll
            for (int q = 0; q < 8; ++q) o[q] = (_Float16)src[q];
            ((half8*)b2pk)[c2] = o;
        } else if (c < 65536 + 512 + 2 * 12288) {
            int idx = c - (65536 + 512);
            const float* src = (idx < 12288) ? w_ih : w_hh;
            float*       dst = (idx < 12288) ? wTih : wThh;
            int e2 = (idx < 12288) ? idx : idx - 12288;
            int k = e2 / 192, g = e2 - k * 192;
            dst[k * 192 + g] = src[(size_t)g * 64 + k];
        }
        return;
    }
    // mlp1: 8 edges per block
    int ebase = (b - G_MS - G_PK) * 8;
    int k = threadIdx.x & 127;
    const float* w = W1 + (size_t)k * EDGE_DIM;
#pragma unroll
    for (int p = 0; p < 4; ++p) {
        int e = ebase + p * 2 + (threadIdx.x >> 7);
        if (e >= N_EDGES) break;
        const float* ea = edge_attr + (size_t)e * EDGE_DIM;
        float acc = b1[k];
#pragma unroll
        for (int d = 0; d < EDGE_DIM; ++d) acc += ea[d] * w[d];
        float g = 0.5f * acc * (1.0f + erff(acc * 0.70710678118654752f));
        h[(size_t)e * HID + k] = (_Float16)g;
    }
}

// ---------------------------------------------------------------- phase 2
// Round-5 body, verbatim. Wave w owns output rows i in [w*16, w*16+16) for
// ALL j. Per j: 4 prefetched A-loads, 16 MFMA into P, f32 gv epilogue.
__global__ __launch_bounds__(256, 3) void edge_msg_mfma_kernel(
    const _Float16* __restrict__ hbuf,
    const float*    __restrict__ x,
    const int*      __restrict__ edge_index,   // [2][E] int32
    const _Float16* __restrict__ Wpk,
    const _Float16* __restrict__ b2pk,
    float* __restrict__ agg)                   // [N][64], pre-zeroed
{
    __shared__ float xsh[64 * 68];      // gathered x[src], pitch 68
    __shared__ float msgred[64 * 67];   // [i][e], pitch 67
    __shared__ int   dsts[64];

    const int e0   = blockIdx.x * 64;
    const int t    = threadIdx.x;
    const int mt   = t >> 6;            // wave = output row block
    const int lane = t & 63;

    // ---- gather x[src[e]] rows into xsh (zero-fill invalid) + dsts
    {
        int le = t >> 2, sub = t & 3;
        int e = e0 + le;
        int s = -1;
        if (e < N_EDGES) {
            if (sub == 0) dsts[le] = edge_index[N_EDGES + e];
            s = edge_index[e];
        } else if (sub == 0) {
            dsts[le] = -1;
        }
#pragma unroll
        for (int q = 0; q < 4; ++q) {
            float4 v = make_float4(0.f, 0.f, 0.f, 0.f);
            if ((unsigned)s < (unsigned)N_NODES)
                v = ((const float4*)x)[(size_t)s * 16 + sub * 4 + q];
            *(float4*)&xsh[le * 68 + sub * 16 + q * 4] = v;
        }
    }

    // ---- per-wave resident h fragments (B operand)
    half8 hf[4][4];   // [nt][ks]
#pragma unroll
    for (int nt = 0; nt < 4; ++nt) {
#pragma unroll
        for (int ks = 0; ks < 4; ++ks) {
            int el = nt * 16 + (lane & 15);
            int ee = e0 + el; if (ee >= N_EDGES) ee = N_EDGES - 1;
            int gk = ks * 32 + ((lane >> 4) & 3) * 8;
            hf[nt][ks] = *(const half8*)(hbuf + (size_t)ee * HID + gk);
        }
    }
    __syncthreads();

    const f32x4 zero4 = {0.f, 0.f, 0.f, 0.f};
    f32x4 msg[4];
#pragma unroll
    for (int nt = 0; nt < 4; ++nt) msg[nt] = zero4;

    const half8* wpk8 = (const half8*)Wpk;
    const int mbase = mt * 64 + lane;

    half8 aA[4], aB[4];
#pragma unroll
    for (int ks = 0; ks < 4; ++ks) aA[ks] = wpk8[(size_t)mbase + ks * 256];  // j=0

#pragma unroll 1
    for (int j = 0; j < 64; j += 2) {
        {   // prefetch j+1
            size_t nb = (size_t)(j + 1) * 1024 + mbase;
#pragma unroll
            for (int ks = 0; ks < 4; ++ks) aB[ks] = wpk8[nb + ks * 256];
        }
        {   // compute j
            float gv[4];
#pragma unroll
            for (int nt = 0; nt < 4; ++nt) gv[nt] = xsh[(nt * 16 + (lane & 15)) * 68 + j];
            f32x4 P[4];
#pragma unroll
            for (int ks = 0; ks < 4; ++ks)
#pragma unroll
                for (int nt = 0; nt < 4; ++nt)
                    P[nt] = __builtin_amdgcn_mfma_f32_16x16x32_f16(
                        aA[ks], hf[nt][ks], ks == 0 ? zero4 : P[nt], 0, 0, 0);
#pragma unroll
            for (int nt = 0; nt < 4; ++nt)
#pragma unroll
                for (int r = 0; r < 4; ++r) msg[nt][r] += gv[nt] * P[nt][r];
        }
        if (j + 2 < 64) {   // prefetch j+2
            size_t nb = (size_t)(j + 2) * 1024 + mbase;
#pragma unroll
            for (int ks = 0; ks < 4; ++ks) aA[ks] = wpk8[nb + ks * 256];
        }
        {   // compute j+1
            float gv[4];
#pragma unroll
            for (int nt = 0; nt < 4; ++nt) gv[nt] = xsh[(nt * 16 + (lane & 15)) * 68 + j + 1];
            f32x4 P[4];
#pragma unroll
            for (int ks = 0; ks < 4; ++ks)
#pragma unroll
                for (int nt = 0; nt < 4; ++nt)
                    P[nt] = __builtin_amdgcn_mfma_f32_16x16x32_f16(
                        aB[ks], hf[nt][ks], ks == 0 ? zero4 : P[nt], 0, 0, 0);
#pragma unroll
            for (int nt = 0; nt < 4; ++nt)
#pragma unroll
                for (int r = 0; r < 4; ++r) msg[nt][r] += gv[nt] * P[nt][r];
        }
    }

    // ---- bias: msg[i,e] += sum_j b2[i*64+j]*g[e,j]  (this wave's rows)
#pragma unroll
    for (int ks2 = 0; ks2 < 2; ++ks2) {
        half8 gf[4];
#pragma unroll
        for (int nt = 0; nt < 4; ++nt) {
            const float* gp = &xsh[(nt * 16 + (lane & 15)) * 68 + ks2 * 32 + ((lane >> 4) & 3) * 8];
            float4 lo = *(const float4*)gp;
            float4 hi = *(const float4*)(gp + 4);
            half8 g8;
            g8[0] = (_Float16)lo.x; g8[1] = (_Float16)lo.y;
            g8[2] = (_Float16)lo.z; g8[3] = (_Float16)lo.w;
            g8[4] = (_Float16)hi.x; g8[5] = (_Float16)hi.y;
            g8[6] = (_Float16)hi.z; g8[7] = (_Float16)hi.w;
            gf[nt] = g8;
        }
        half8 bf8 = ((const half8*)b2pk)[ks2 * 256 + mt * 64 + lane];
#pragma unroll
        for (int nt = 0; nt < 4; ++nt)
            msg[nt] = __builtin_amdgcn_mfma_f32_16x16x32_f16(bf8, gf[nt], msg[nt], 0, 0, 0);
    }

    // ---- each wave writes its exclusive 16 rows of msgred
#pragma unroll
    for (int nt = 0; nt < 4; ++nt)
#pragma unroll
        for (int r = 0; r < 4; ++r) {
            int i = mt * 16 + ((lane >> 4) & 3) * 4 + r;
            int e = nt * 16 + (lane & 15);
            msgred[i * 67 + e] = msg[nt][r];
        }
    __syncthreads();

    // ---- scatter, coalesced: one edge row per atomic instr (lane = dim i)
#pragma unroll 1
    for (int ee = mt; ee < 64; ee += 4) {
        int d = dsts[ee];
        if (e0 + ee < N_EDGES && (unsigned)d < (unsigned)N_NODES)
            atomicAdd(agg + (size_t)d * NODE_DIM + lane, msgred[lane * 67 + ee]);
    }
}

// ---------------------------------------------------------------- phase 3
// GRUCell, transposed-LDS staging: asT/xsT[wave][k][node] (pitch 12, rows
// 16B-aligned). Per k: 4 same-address broadcast ds_read_b128 (conflict-free)
// instead of 16 scalar column reads. Blend re-reads x from global (L2-hot).
__global__ __launch_bounds__(256) void gru_kernel(
    const float* __restrict__ agg,
    const float* __restrict__ x,
    const float* __restrict__ wTih,   // [64][192]
    const float* __restrict__ wThh,   // [64][192]
    const float* __restrict__ b_ih,
    const float* __restrict__ b_hh,
    float* __restrict__ out)
{
    __shared__ float asT[4][64][12];  // [wave][k][node], 12-pitch -> aligned
    __shared__ float xsT[4][64][12];
    const int t    = threadIdx.x;
    const int wave = t >> 6, lane = t & 63;
    const int n0   = blockIdx.x * 32;

    {   // stage transposed: global float4 (node-major) -> LDS [k][node]
        const f32x4* asrc = (const f32x4*)(agg + (size_t)n0 * 64);
        const f32x4* xsrc = (const f32x4*)(x   + (size_t)n0 * 64);
        int nvalid4 = min(N_NODES - n0, 32) * 16;
#pragma unroll
        for (int r = 0; r < 2; ++r) {
            int idx = t + r * 256;            // node le = idx>>4, quad q = idx&15
            f32x4 v = {0.f, 0.f, 0.f, 0.f}, u = v;
            if (idx < nvalid4) { v = asrc[idx]; u = xsrc[idx]; }
            int le = idx >> 4, q = idx & 15;
#pragma unroll
            for (int c = 0; c < 4; ++c) {
                asT[le >> 3][q * 4 + c][le & 7] = v[c];
                xsT[le >> 3][q * 4 + c][le & 7] = u[c];
            }
        }
    }
    __syncthreads();

    float accI0[8] = {}, accI1[8] = {}, accI2[8] = {};
    float accH0[8] = {}, accH1[8] = {}, accH2[8] = {};

#pragma unroll 4
    for (int k = 0; k < 64; ++k) {
        f32x4 a03 = *(const f32x4*)&asT[wave][k][0];
        f32x4 a47 = *(const f32x4*)&asT[wave][k][4];
        f32x4 x03 = *(const f32x4*)&xsT[wave][k][0];
        f32x4 x47 = *(const f32x4*)&xsT[wave][k][4];
        float wi0 = wTih[k * 192 + lane];
        float wi1 = wTih[k * 192 + 64 + lane];
        float wi2 = wTih[k * 192 + 128 + lane];
        float wh0 = wThh[k * 192 + lane];
        float wh1 = wThh[k * 192 + 64 + lane];
        float wh2 = wThh[k * 192 + 128 + lane];
#pragma unroll
        for (int n = 0; n < 8; ++n) {
            float a  = (n < 4) ? a03[n] : a47[n - 4];
            float xx = (n < 4) ? x03[n] : x47[n - 4];
            accI0[n] += a * wi0;  accI1[n] += a * wi1;  accI2[n] += a * wi2;
            accH0[n] += xx * wh0; accH1[n] += xx * wh1; accH2[n] += xx * wh2;
        }
    }

    float bi0 = b_ih[lane], bi1 = b_ih[64 + lane], bi2 = b_ih[128 + lane];
    float bh0 = b_hh[lane], bh1 = b_hh[64 + lane], bh2 = b_hh[128 + lane];
#pragma unroll
    for (int n = 0; n < 8; ++n) {
        int node = n0 + wave * 8 + n;
        if (node >= N_NODES) break;
        float r  = 1.f / (1.f + expf(-(accI0[n] + bi0 + accH0[n] + bh0)));
        float z  = 1.f / (1.f + expf(-(accI1[n] + bi1 + accH1[n] + bh1)));
        float nn = tanhf(accI2[n] + bi2 + r * (accH2[n] + bh2));
        float xv = x[(size_t)node * 64 + lane];          // coalesced, L2-hot
        out[(size_t)node * 64 + lane] = (1.f - z) * nn + z * xv;
    }
}

// ---------------------------------------------------------------- launch
extern "C" void kernel_launch(void* const* d_in, const int* in_sizes, int n_in,
                              void* d_out, int out_size, void* d_ws, size_t ws_size,
                              hipStream_t stream)
{
    const float* x          = (const float*)d_in[0];
    const int*   edge_index = (const int*)  d_in[1];
    const float* edge_attr  = (const float*)d_in[2];
    const float* W1         = (const float*)d_in[3];
    const float* b1         = (const float*)d_in[4];
    const float* W2         = (const float*)d_in[5];
    const float* b2         = (const float*)d_in[6];
    const float* w_ih       = (const float*)d_in[7];
    const float* w_hh       = (const float*)d_in[8];
    const float* b_ih       = (const float*)d_in[9];
    const float* b_hh       = (const float*)d_in[10];
    float* out = (float*)d_out;

    // ws layout: byte-identical to round 5 (proven; total 20,355,072 B)
    char* ws = (char*)d_ws;
    _Float16* hbuf = (_Float16*)ws;                         // 12.8 MB
    ws += (size_t)N_EDGES * HID * sizeof(_Float16);
    _Float16* Wpk  = (_Float16*)ws;                         // 1 MB
    ws += (size_t)65536 * 8 * sizeof(_Float16);
    _Float16* b2pk = (_Float16*)ws;                         // 8 KB
    ws += (size_t)512 * 8 * sizeof(_Float16);
    float* wTih = (float*)ws;                               // 48 KB
    ws += (size_t)64 * 192 * sizeof(float);
    float* wThh = (float*)ws;                               // 48 KB
    ws += (size_t)64 * 192 * sizeof(float);
    float* agg = (float*)ws;                                // 6.4 MB

    prep_kernel<<<dim3(G_MS + G_PK + G_MLP), dim3(256), 0, stream>>>(
        W2, b2, w_ih, w_hh, edge_attr, W1, b1,
        Wpk, b2pk, wTih, wThh, hbuf, agg);

    edge_msg_mfma_kernel<<<dim3((N_EDGES + 63) / 64), dim3(256), 0, stream>>>(
        hbuf, x, edge_index, Wpk, b2pk, agg);

    gru_kernel<<<dim3((N_NODES + 31) / 32), dim3(256), 0, stream>>>(
        agg, x, wTih, wThh, b_ih, b_hh, out);
}